// Round 1
// baseline (343.797 us; speedup 1.0000x reference)
//
#include <hip/hip_runtime.h>
#include <hip/hip_bf16.h>

#define FEAT    512
#define HEADS   4
#define NEG     0.2f

typedef unsigned int uint;
typedef unsigned short ushort_t;
typedef __attribute__((ext_vector_type(8))) short bf16x8v;   // 8 bf16 = 4 VGPRs
typedef __attribute__((ext_vector_type(4))) float f32x4v;    // mfma acc
typedef __attribute__((address_space(3))) uint lds_u32_t;
typedef __attribute__((address_space(1))) const uint g_u32_t;

__device__ inline float bf2f(ushort_t h) { return __uint_as_float(((uint)h) << 16); }
__device__ inline ushort_t f2bf(float f) {
    uint u = __float_as_uint(f);
    u += 0x7fff + ((u >> 16) & 1);           // RNE
    return (ushort_t)(u >> 16);
}
__device__ inline float2 up2(uint d) {       // 2 packed bf16 -> float2, 2 inst
    return make_float2(__uint_as_float(d << 16), __uint_as_float(d & 0xffff0000u));
}
__device__ inline float2 f2add(float2 a, float2 b) { return make_float2(a.x + b.x, a.y + b.y); }
__device__ inline float2 f2min0(float2 a) { return make_float2(fminf(a.x, 0.f), fminf(a.y, 0.f)); }
__device__ inline float2 f2fma(float2 a, float2 b, float2 c) {
    return make_float2(fmaf(a.x, b.x, c.x), fmaf(a.y, b.y, c.y));
}
__device__ inline float2 f2fmas(float s, float2 b, float2 c) {
    return make_float2(fmaf(s, b.x, c.x), fmaf(s, b.y, c.y));
}

// ---------------------------------------------------------------------------
// fused prep: dtype probe (per-block, from the same 256B of x -> no cross-block
// dep), deg zeroing, small-array canon, and x canon. 1 dispatch replaces 4.
// block roles: [0,NBZ) zero deg | [NBZ,NBZ+15) canon small4 | rest canon x.
// ---------------------------------------------------------------------------
__global__ __launch_bounds__(256) void prep_kernel(
    const ushort_t* __restrict__ xprobe, int* flag,
    int* __restrict__ deg, int N, int NBZ,
    const void* a0, ushort_t* o0, int n0, const void* a1, ushort_t* o1, int n1,
    const void* a2, ushort_t* o2, int n2, const void* a3, ushort_t* o3, int n3,
    const void* __restrict__ xin, ushort_t* __restrict__ xc, long long nx) {
    __shared__ int s_isbf;
    int tid = threadIdx.x;
    if (tid < 64) {
        int hits = 0;
        for (int i = tid; i < 128; i += 64) {
            ushort_t w = xprobe[2 * i];
            uint hb = (w >> 8) & 0x7f;
            hits += (hb >= 0x38 && hb <= 0x42) ? 1 : 0;
        }
        #pragma unroll
        for (int off = 32; off >= 1; off >>= 1) hits += __shfl_xor(hits, off);
        if (tid == 0) s_isbf = (hits >= 64) ? 1 : 0;
    }
    __syncthreads();
    int isbf = s_isbf;
    int b = blockIdx.x;
    if (b == 0 && tid == 0) *flag = isbf;

    if (b < NBZ) {                       // zero deg (int4)
        int i0 = (b * 256 + tid) * 4;
        if (i0 + 4 <= N) *(int4*)&deg[i0] = make_int4(0, 0, 0, 0);
        else for (int j = 0; j < 4; ++j) if (i0 + j < N) deg[i0 + j] = 0;
        return;
    }
    if (b < NBZ + 15) {                  // canon small4
        int idx = (b - NBZ) * 256 + tid;
        const void* srcs[4] = {a0, a1, a2, a3};
        ushort_t* dsts[4] = {o0, o1, o2, o3};
        int ns[4] = {n0, n1, n2, n3};
        #pragma unroll
        for (int k = 0; k < 4; ++k) {
            if (idx < ns[k]) {
                dsts[k][idx] = isbf ? ((const ushort_t*)srcs[k])[idx]
                                    : f2bf(((const float*)srcs[k])[idx]);
                return;
            }
            idx -= ns[k];
        }
        return;
    }
    if (isbf) return;                    // x used directly when already bf16
    long long i0 = ((long long)(b - NBZ - 15) * 256 + tid) * 8;
    if (i0 + 8 <= nx) {
        const float* f = (const float*)xin + i0;
        float4 a = *(const float4*)f, bb = *(const float4*)(f + 4);
        ushort_t o[8] = {f2bf(a.x), f2bf(a.y), f2bf(a.z), f2bf(a.w),
                         f2bf(bb.x), f2bf(bb.y), f2bf(bb.z), f2bf(bb.w)};
        *(uint4*)&xc[i0] = *(uint4*)o;
    } else {
        for (long long i = i0; i < nx; ++i) xc[i] = f2bf(((const float*)xin)[i]);
    }
}

// ---------------------------------------------------------------------------
// CSR build by dst
// ---------------------------------------------------------------------------
__global__ void hist_kernel(const int* __restrict__ dst, int* deg, int E, int N) {
    int i = blockIdx.x * blockDim.x + threadIdx.x;
    if (i < E) {
        int d = dst[i];
        if ((uint)d < (uint)N) atomicAdd(&deg[d], 1);
    }
}

// phase 1: per-1024-block exclusive scan over (deg[i] + 1)  [+1 = self-loop]
__global__ __launch_bounds__(256) void scan1(const int* __restrict__ deg, int* __restrict__ part,
                                             int* __restrict__ bsum, int N) {
    __shared__ int tmp[256];
    int b = blockIdx.x, tid = threadIdx.x;
    int i0 = b * 1024 + tid * 4;
    int v[4] = {0, 0, 0, 0};
    if (i0 + 4 <= N) { int4 q = *(const int4*)&deg[i0]; v[0]=q.x+1; v[1]=q.y+1; v[2]=q.z+1; v[3]=q.w+1; }
    else { for (int j = 0; j < 4; ++j) v[j] = (i0 + j < N) ? deg[i0 + j] + 1 : 0; }
    int s0 = v[0], s1 = s0 + v[1], s2 = s1 + v[2], s3 = s2 + v[3];
    tmp[tid] = s3;
    __syncthreads();
    for (int off = 1; off < 256; off <<= 1) {
        int t = (tid >= off) ? tmp[tid - off] : 0;
        __syncthreads();
        tmp[tid] += t;
        __syncthreads();
    }
    int base = tid ? tmp[tid - 1] : 0;
    int e[4] = {base, base + s0, base + s1, base + s2};
    if (i0 + 4 <= N) { *(int4*)&part[i0] = make_int4(e[0], e[1], e[2], e[3]); }
    else { for (int j = 0; j < 4; ++j) if (i0 + j < N) part[i0 + j] = e[j]; }
    if (tid == 255) bsum[b] = tmp[255];
}

// phase 2 (fused): each block wave-scans the Nb block sums itself (Nb <= 64)
__global__ __launch_bounds__(256) void scan3(const int* __restrict__ part, const int* __restrict__ bsum,
                                             int* __restrict__ offsets, int* __restrict__ cursor,
                                             int N, int Nb) {
    __shared__ int s_add, s_tot;
    int b = blockIdx.x, tid = threadIdx.x;
    if (tid < 64) {
        int v = (tid < Nb) ? bsum[tid] : 0;
        int incl = v;
        #pragma unroll
        for (int off = 1; off < 64; off <<= 1) {
            int t = __shfl_up(incl, off);
            if (tid >= off) incl += t;
        }
        if (tid == b) s_add = incl - v;
        if (tid == Nb - 1) s_tot = incl;
    }
    __syncthreads();
    int add = s_add;
    int i0 = b * 1024 + tid * 4;
    #pragma unroll
    for (int j = 0; j < 4; ++j) {
        int i = i0 + j;
        if (i < N) { int o = part[i] + add; offsets[i] = o; cursor[i] = o; }
    }
    if (b == Nb - 1 && tid == 0) offsets[N] = s_tot;   // = E + N
}

__global__ void scatter_kernel(const int* __restrict__ src, const int* __restrict__ dst,
                               int* cursor, int* srcs, int E, int N) {
    int i = blockIdx.x * blockDim.x + threadIdx.x;
    if (i >= E + N) return;
    int s, d;
    if (i < E) { s = src[i]; d = dst[i]; }
    else       { s = i - E; d = i - E; }   // self-loop
    if ((uint)d >= (uint)N) return;
    int pos = atomicAdd(&cursor[d], 1);
    if ((uint)pos < (uint)(E + N)) srcs[pos] = s;
}

// ---------------------------------------------------------------------------
// dual-dtype transpose+canon for BOTH weight matrices in one dispatch (z = 0/1)
// out[N][K] (bf16) = in[K][N] (bf16 or fp32)
// ---------------------------------------------------------------------------
__global__ __launch_bounds__(256) void transpose_canon2(const void* __restrict__ inL,
                                                        const void* __restrict__ inR,
                                                        ushort_t* __restrict__ outL,
                                                        ushort_t* __restrict__ outR,
                                                        const int* __restrict__ flag,
                                                        int K, int N) {
    __shared__ ushort_t t[64][72];
    const void* in = blockIdx.z ? inR : inL;
    ushort_t* outp = blockIdx.z ? outR : outL;
    int k0 = blockIdx.y * 64, n0 = blockIdx.x * 64;
    int tid = threadIdx.x;
    int r = tid >> 3;            // 0..31
    int c = (tid & 7) * 8;       // 0,8,..,56
    int isbf = *flag;
    #pragma unroll
    for (int p = 0; p < 2; ++p) {
        int row = r + p * 32;
        size_t base = (size_t)(k0 + row) * N + n0 + c;
        if (isbf) {
            *(uint4*)&t[row][c] = *(const uint4*)((const ushort_t*)in + base);
        } else {
            const float* f = (const float*)in + base;
            float4 a = *(const float4*)f, b = *(const float4*)(f + 4);
            ushort_t o[8] = {f2bf(a.x), f2bf(a.y), f2bf(a.z), f2bf(a.w),
                             f2bf(b.x), f2bf(b.y), f2bf(b.z), f2bf(b.w)};
            *(uint4*)&t[row][c] = *(uint4*)o;
        }
    }
    __syncthreads();
    #pragma unroll
    for (int p = 0; p < 2; ++p) {
        int row = r + p * 32;
        #pragma unroll
        for (int j = 0; j < 8; ++j)
            outp[(size_t)(n0 + row) * K + k0 + c + j] = t[c + j][row];
    }
}

// ---------------------------------------------------------------------------
// MFMA bf16 GEMM: C[M,N] = A[M,K] @ Bt[N,K]^T. 128x128 tile, 4 waves of 64x64.
// BK=64 via two k-panels per staging iter (r10 structure). blockIdx.x = COL
// tile (r10 order; row-fast re-streamed A 32x — measured r12). Epilogue
// bounces C through LDS (stride 132) -> 16B coalesced stores (r14).
// ---------------------------------------------------------------------------
__global__ __launch_bounds__(256) void gemm128(const ushort_t* A_bf, const ushort_t* A_cv,
                                               const int* __restrict__ flag,
                                               const ushort_t* __restrict__ Bt,
                                               ushort_t* __restrict__ C,
                                               int M, int Nn, int K) {
    constexpr int CSTR = 132;                 // epilogue row stride (bank spread)
    __shared__ ushort_t SH[128 * CSTR];       // 33792 B; staging uses first 32KB
    ushort_t* As = SH;                        // As[2][4096]
    ushort_t* Bs = SH + 8192;                 // Bs[2][4096]
    const ushort_t* A = (*flag) ? A_bf : A_cv;
    int tid = threadIdx.x;
    int wave = tid >> 6, lane = tid & 63;
    int row0 = blockIdx.y * 128, col0 = blockIdx.x * 128;
    int wm = (wave >> 1) * 64, wn = (wave & 1) * 64;

    f32x4v acc[4][4];
    #pragma unroll
    for (int i = 0; i < 4; ++i)
        #pragma unroll
        for (int j = 0; j < 4; ++j) acc[i][j] = (f32x4v){0.f, 0.f, 0.f, 0.f};

    int fm = lane & 15, kq8 = (lane >> 4) * 8;

    // staging (r6 mapping, coalesced 64B runs): chunk p -> row=p>>2, kp=p&3
    const ushort_t* srcA[2]; ushort_t* dstA0[2]; ushort_t* dstA1[2];
    const ushort_t* srcB[2]; ushort_t* dstB0[2]; ushort_t* dstB1[2];
    #pragma unroll
    for (int i = 0; i < 2; ++i) {
        int p = (wave * 2 + i) * 64 + lane;
        int row = p >> 2, kp = p & 3;
        int gra = row0 + row; if (gra >= M) gra = M - 1;   // tail clamp (C-write guarded)
        srcA[i] = &A[(size_t)gra * K + kp * 8];
        srcB[i] = &Bt[(size_t)(col0 + row) * K + kp * 8];
        dstA0[i] = &As[p * 8]; dstA1[i] = &As[4096 + p * 8];
        dstB0[i] = &Bs[p * 8]; dstB1[i] = &Bs[4096 + p * 8];
    }

    for (int k0 = 0; k0 < K; k0 += 64) {
        #pragma unroll
        for (int i = 0; i < 2; ++i) {
            __builtin_amdgcn_global_load_lds((g_u32_t*)srcA[i],        (lds_u32_t*)dstA0[i], 16, 0, 0);
            __builtin_amdgcn_global_load_lds((g_u32_t*)(srcA[i] + 32), (lds_u32_t*)dstA1[i], 16, 0, 0);
            __builtin_amdgcn_global_load_lds((g_u32_t*)srcB[i],        (lds_u32_t*)dstB0[i], 16, 0, 0);
            __builtin_amdgcn_global_load_lds((g_u32_t*)(srcB[i] + 32), (lds_u32_t*)dstB1[i], 16, 0, 0);
            srcA[i] += 64; srcB[i] += 64;
        }
        __syncthreads();

        #pragma unroll
        for (int panel = 0; panel < 2; ++panel) {
            bf16x8v af[4], bfr[4];
            #pragma unroll
            for (int mi = 0; mi < 4; ++mi)
                af[mi] = *(const bf16x8v*)&As[panel * 4096 + (wm + mi * 16 + fm) * 32 + kq8];
            #pragma unroll
            for (int nj = 0; nj < 4; ++nj)
                bfr[nj] = *(const bf16x8v*)&Bs[panel * 4096 + (wn + nj * 16 + fm) * 32 + kq8];
            #pragma unroll
            for (int mi = 0; mi < 4; ++mi)
                #pragma unroll
                for (int nj = 0; nj < 4; ++nj)
                    acc[mi][nj] = __builtin_amdgcn_mfma_f32_16x16x32_bf16(af[mi], bfr[nj], acc[mi][nj], 0, 0, 0);
        }
        __syncthreads();
    }

    // epilogue: C/D layout col = lane&15, row = (lane>>4)*4 + r  [verified r4-r14]
    int col = lane & 15, rq = (lane >> 4) * 4;
    #pragma unroll
    for (int mi = 0; mi < 4; ++mi)
        #pragma unroll
        for (int r = 0; r < 4; ++r)
            #pragma unroll
            for (int nj = 0; nj < 4; ++nj)
                SH[(wm + mi * 16 + rq + r) * CSTR + wn + nj * 16 + col] = f2bf(acc[mi][nj][r]);
    __syncthreads();
    #pragma unroll
    for (int j = 0; j < 8; ++j) {
        int base = (tid + j * 256) * 8;        // idx in 128x128 space
        int r = base >> 7, c = base & 127;
        int gm = row0 + r;
        if (gm < M)
            *(uint4*)&C[(size_t)gm * Nn + col0 + c] = *(const uint4*)&SH[r * CSTR + c];
    }
}

// ---------------------------------------------------------------------------
// Fused edge/softmax/aggregate/mean-heads/bias/classifier. OUTPUT FP32.
// R1 restructure: block = 128 threads = 2 waves per dst node; each wave owns
// TWO heads (wave w -> heads 2w, 2w+1). Lane l: head h = 2w + (l>>5),
// channels (l&31)*16 .. +16 (two contiguous uint4 per edge row; the wave's
// 64 lanes cover a contiguous 2KB, still fully coalesced). Score reduce is a
// 5-step butterfly WITHIN each 32-lane half (xor offsets 16..1 never cross
// the half), giving both heads' scores in one pass. Rationale: the previous
// 4-wave/1-head layout measured ~157 wave-inst per edge PER WAVE (VALUBusy
// 77%, HBM 41% -> VALU-issue-bound); per-wave-replicated overhead (src shfl,
// addr math, loop ctrl, 6-step butterfly, exp, reg rotation) was ~4x
// redundant. Halving waves/edge halves that overhead; intrinsic channel math
// is unchanged. 2-edge-pair prefetch pipeline (distance 2).
// ---------------------------------------------------------------------------
__global__ __launch_bounds__(128, 4) void gat_aggregate(
    const ushort_t* __restrict__ xl, int xl_stride,
    const ushort_t* __restrict__ xr, int xr_stride,
    const int* __restrict__ offsets, const int* __restrict__ srcs,
    const ushort_t* __restrict__ att, const ushort_t* __restrict__ bias,
    const ushort_t* __restrict__ Wc, const ushort_t* __restrict__ bc,
    float* __restrict__ out, int c0, int Cn, int N, int EN) {
    int bn = blockIdx.x;
    if (bn >= Cn) return;
    int n = c0 + bn;
    int tid = threadIdx.x;
    int w = tid >> 6, lane = tid & 63;
    int h = 2 * w + (lane >> 5);             // this lane's head
    int r = lane & 31;                       // 32 lanes per head
    int hoff = h * FEAT + r * 16;            // 16 channels per lane

    __shared__ float sh[HEADS][FEAT];
    __shared__ float r0s[2], r1s[2];

    float2 xrr[8], attr[8];
    { const ushort_t* p = &xr[(size_t)bn * xr_stride + hoff];
      uint4 qa = *(const uint4*)p, qb = *(const uint4*)(p + 8);
      xrr[0] = up2(qa.x); xrr[1] = up2(qa.y); xrr[2] = up2(qa.z); xrr[3] = up2(qa.w);
      xrr[4] = up2(qb.x); xrr[5] = up2(qb.y); xrr[6] = up2(qb.z); xrr[7] = up2(qb.w); }
    { const ushort_t* p = &att[hoff];
      uint4 qa = *(const uint4*)p, qb = *(const uint4*)(p + 8);
      attr[0] = up2(qa.x); attr[1] = up2(qa.y); attr[2] = up2(qa.z); attr[3] = up2(qa.w);
      attr[4] = up2(qb.x); attr[5] = up2(qb.y); attr[6] = up2(qb.z); attr[7] = up2(qb.w); }

    int start = offsets[n], end = offsets[n + 1];
    start = max(0, min(start, EN));
    end   = max(start, min(end, EN));
    int deg = end - start;

    int sv = 0;
    if (lane < deg) sv = srcs[start + lane];

    float l = 0.f;
    float2 acc[8] = {{0.f,0.f},{0.f,0.f},{0.f,0.f},{0.f,0.f},
                     {0.f,0.f},{0.f,0.f},{0.f,0.f},{0.f,0.f}};
    const ushort_t* xlh = xl + hoff;
    const float2 cneg = make_float2(NEG - 1.0f, NEG - 1.0f);

    auto getS = [&](int i) -> int {
        if (i >= deg) i = deg - 1;
        if (i < 0) i = 0;
        int s = (i < 64) ? __shfl(sv, i) : srcs[start + i];
        return ((uint)s >= (uint)N) ? 0 : s;
    };
    auto fetchE = [&](int i, uint4& qa, uint4& qb) {
        int s = getS(i);
        const ushort_t* pp = xlh + (size_t)s * xl_stride;
        qa = *(const uint4*)pp;
        qb = *(const uint4*)(pp + 8);
    };
    auto body = [&](uint4 qa, uint4 qb) {
        float2 v[8] = {up2(qa.x), up2(qa.y), up2(qa.z), up2(qa.w),
                       up2(qb.x), up2(qb.y), up2(qb.z), up2(qb.w)};
        float2 p2 = make_float2(0.f, 0.f);
        #pragma unroll
        for (int j = 0; j < 8; ++j) {
            float2 u  = f2add(v[j], xrr[j]);
            float2 lr = f2fma(f2min0(u), cneg, u);   // 2-op LeakyReLU (packed)
            p2 = f2fma(lr, attr[j], p2);
        }
        float p = p2.x + p2.y;
        #pragma unroll
        for (int off = 16; off >= 1; off >>= 1) p += __shfl_xor(p, off);  // intra-half
        float wgt = __expf(p);
        l += wgt;
        #pragma unroll
        for (int j = 0; j < 8; ++j) acc[j] = f2fmas(wgt, v[j], acc[j]);
    };

    uint4 a0q, a0r, a1q, a1r, b0q, b0r, b1q, b1r;
    fetchE(0, a0q, a0r);
    fetchE(1, a1q, a1r);
    for (int e = 0; e < deg; e += 2) {
        fetchE(e + 2, b0q, b0r);     // clamped on tail -> L1 hit, discarded
        fetchE(e + 3, b1q, b1r);
        body(a0q, a0r);
        if (e + 1 < deg) body(a1q, a1r);
        a0q = b0q; a0r = b0r; a1q = b1q; a1r = b1r;
    }

    float inv = 0.25f / fmaxf(l, 1e-35f);   // 1/l, mean over heads folded in
    #pragma unroll
    for (int j = 0; j < 8; ++j) {
        sh[h][r * 16 + 2 * j]     = acc[j].x * inv;
        sh[h][r * 16 + 2 * j + 1] = acc[j].y * inv;
    }
    __syncthreads();

    float p0 = 0.f, p1 = 0.f;
    #pragma unroll
    for (int c = tid; c < FEAT; c += 128) {
        float f = sh[0][c] + sh[1][c] + sh[2][c] + sh[3][c] + bf2f(bias[c]);
        uint w2 = *(const uint*)&Wc[c * 2];
        p0 = fmaf(f, bf2f((ushort_t)(w2 & 0xffff)), p0);
        p1 = fmaf(f, bf2f((ushort_t)(w2 >> 16)), p1);
    }
    #pragma unroll
    for (int off = 32; off >= 1; off >>= 1) {
        p0 += __shfl_xor(p0, off);
        p1 += __shfl_xor(p1, off);
    }
    if (lane == 0) { r0s[w] = p0; r1s[w] = p1; }
    __syncthreads();
    if (tid == 0) {
        out[(size_t)n * 2 + 0] = r0s[0] + r0s[1] + bf2f(bc[0]);
        out[(size_t)n * 2 + 1] = r1s[0] + r1s[1] + bf2f(bc[1]);
    }
}

// ---------------------------------------------------------------------------
extern "C" void kernel_launch(void* const* d_in, const int* in_sizes, int n_in,
                              void* d_out, int out_size, void* d_ws, size_t ws_size,
                              hipStream_t stream) {
    const void* x    = d_in[0];
    const int*  ei   = (const int*)d_in[1];
    const void* W_l  = d_in[2];
    const void* W_r  = d_in[3];
    const void* att  = d_in[4];
    const void* bias = d_in[5];
    const void* Wc   = d_in[6];
    const void* bc   = d_in[7];
    float* out = (float*)d_out;

    const int N  = in_sizes[0] / FEAT;     // 20000
    const int E  = in_sizes[1] / 2;        // 160000
    const int K  = FEAT;                   // 512
    const int HC = HEADS * FEAT;           // 2048
    const int EN = E + N;
    const int Nb = (N + 1023) / 1024;      // scan blocks (20 <= 64)

    const int* src = ei;
    const int* dst = ei + E;

    // ---- adaptive workspace layout ----
    char* base = (char*)d_ws;
    size_t off = 0;
    auto alloc = [&](size_t bytes) -> char* {
        char* p = base + off;
        off = (off + bytes + 255) & ~(size_t)255;
        return p;
    };
    int* flag    = (int*)alloc(4);
    int* offsets = (int*)alloc((size_t)(N + 1) * 4);
    int* cursor  = (int*)alloc((size_t)N * 4);
    int* deg     = (int*)alloc((size_t)N * 4);
    int* part    = (int*)alloc((size_t)N * 4);
    int* bsum    = (int*)alloc((size_t)(Nb + 1) * 4);
    int* srcs    = (int*)alloc((size_t)EN * 4);
    ushort_t* attc  = (ushort_t*)alloc((size_t)HC * 2);
    ushort_t* biasc = (ushort_t*)alloc((size_t)FEAT * 2);
    ushort_t* Wcc   = (ushort_t*)alloc((size_t)FEAT * 2 * 2);
    ushort_t* bcc   = (ushort_t*)alloc(2 * 2);
    ushort_t* xc   = (ushort_t*)alloc((size_t)N * K * 2);
    ushort_t* Wcat = (ushort_t*)alloc((size_t)2 * HC * K * 2);   // [Wl^T ; Wr^T]
    size_t fixed = off;

    size_t need_merged = (size_t)N * 2 * HC * 2;
    bool merged = (ws_size >= fixed + need_merged);

    // 0) fused prep: probe + deg-zero + small canon + x canon (1 dispatch)
    long long NX = (long long)N * K;
    const int NBZ = (N + 1023) / 1024;                       // deg-zero blocks
    int nxb = (int)((NX / 8 + 255) / 256);                   // x canon blocks
    prep_kernel<<<NBZ + 15 + nxb, 256, 0, stream>>>(
        (const ushort_t*)x, flag, deg, N, NBZ,
        att, attc, HC, bias, biasc, FEAT, Wc, Wcc, FEAT * 2, bc, bcc, 2,
        x, xc, NX);

    // 1) CSR build
    hist_kernel<<<(E + 255) / 256, 256, 0, stream>>>(dst, deg, E, N);
    scan1<<<Nb, 256, 0, stream>>>(deg, part, bsum, N);
    scan3<<<Nb, 256, 0, stream>>>(part, bsum, offsets, cursor, N, Nb);
    scatter_kernel<<<(EN + 255) / 256, 256, 0, stream>>>(src, dst, cursor, srcs, E, N);

    // 2) transpose+canon both weights in one dispatch
    dim3 tg(HC / 64, K / 64, 2);
    transpose_canon2<<<tg, 256, 0, stream>>>(W_l, W_r, Wcat, Wcat + (size_t)HC * K,
                                             flag, K, HC);

    const ushort_t* x_bf = (const ushort_t*)x;

    if (merged) {
        ushort_t* xlr = (ushort_t*)(base + fixed);       // N x 4096: [xl | xr]
        dim3 gg(2 * HC / 128, (N + 127) / 128);          // x = col tiles (r10 order)
        gemm128<<<gg, 256, 0, stream>>>(x_bf, xc, flag, Wcat, xlr, N, 2 * HC, K);
        gat_aggregate<<<N, 128, 0, stream>>>(xlr, 2 * HC, xlr + HC, 2 * HC,
                                             offsets, srcs, attc, biasc, Wcc, bcc,
                                             out, 0, N, N, EN);
    } else {
        // fallback: separate xl + chunked xr
        ushort_t* xl = (ushort_t*)alloc((size_t)N * HC * 2);
        size_t remain = (ws_size > off) ? (ws_size - off) : 0;
        long long Cmax = (long long)(remain / ((size_t)HC * 2));
        int C = (Cmax >= N) ? N : (int)(Cmax & ~63LL);
        if (C < 64) C = 64;
        ushort_t* xrc = (ushort_t*)(base + off);
        ushort_t* Wlt = Wcat;
        ushort_t* Wrt = Wcat + (size_t)HC * K;

        dim3 gl(HC / 128, (N + 127) / 128);
        gemm128<<<gl, 256, 0, stream>>>(x_bf, xc, flag, Wlt, xl, N, HC, K);
        for (int c0 = 0; c0 < N; c0 += C) {
            int Cn = (N - c0 < C) ? (N - c0) : C;
            dim3 gr(HC / 128, (Cn + 127) / 128);
            gemm128<<<gr, 256, 0, stream>>>(x_bf + (size_t)c0 * K, xc + (size_t)c0 * K, flag,
                                            Wrt, xrc, Cn, HC, K);
            gat_aggregate<<<Cn, 128, 0, stream>>>(xl, HC, xrc, HC,
                                                  offsets, srcs, attc, biasc, Wcc, bcc,
                                                  out, c0, Cn, N, EN);
        }
    }
}

// Round 2
// 341.505 us; speedup vs baseline: 1.0067x; 1.0067x over previous
//
#include <hip/hip_runtime.h>
#include <hip/hip_bf16.h>

#define FEAT    512
#define HEADS   4
#define NEG     0.2f

typedef unsigned int uint;
typedef unsigned short ushort_t;
typedef __attribute__((ext_vector_type(8))) short bf16x8v;   // 8 bf16 = 4 VGPRs
typedef __attribute__((ext_vector_type(4))) float f32x4v;    // mfma acc
typedef __attribute__((address_space(3))) uint lds_u32_t;
typedef __attribute__((address_space(1))) const uint g_u32_t;

__device__ inline float bf2f(ushort_t h) { return __uint_as_float(((uint)h) << 16); }
__device__ inline ushort_t f2bf(float f) {
    uint u = __float_as_uint(f);
    u += 0x7fff + ((u >> 16) & 1);           // RNE
    return (ushort_t)(u >> 16);
}
__device__ inline float2 up2(uint d) {       // 2 packed bf16 -> float2, 2 inst
    return make_float2(__uint_as_float(d << 16), __uint_as_float(d & 0xffff0000u));
}
__device__ inline float2 f2add(float2 a, float2 b) { return make_float2(a.x + b.x, a.y + b.y); }
__device__ inline float2 f2min0(float2 a) { return make_float2(fminf(a.x, 0.f), fminf(a.y, 0.f)); }
__device__ inline float2 f2fma(float2 a, float2 b, float2 c) {
    return make_float2(fmaf(a.x, b.x, c.x), fmaf(a.y, b.y, c.y));
}
__device__ inline float2 f2fmas(float s, float2 b, float2 c) {
    return make_float2(fmaf(s, b.x, c.x), fmaf(s, b.y, c.y));
}

// ---------------------------------------------------------------------------
// fused prep: dtype probe (per-block, from the same 256B of x -> no cross-block
// dep), deg zeroing, small-array canon, and x canon. 1 dispatch replaces 4.
// block roles: [0,NBZ) zero deg | [NBZ,NBZ+15) canon small4 | rest canon x.
// ---------------------------------------------------------------------------
__global__ __launch_bounds__(256) void prep_kernel(
    const ushort_t* __restrict__ xprobe, int* flag,
    int* __restrict__ deg, int N, int NBZ,
    const void* a0, ushort_t* o0, int n0, const void* a1, ushort_t* o1, int n1,
    const void* a2, ushort_t* o2, int n2, const void* a3, ushort_t* o3, int n3,
    const void* __restrict__ xin, ushort_t* __restrict__ xc, long long nx) {
    __shared__ int s_isbf;
    int tid = threadIdx.x;
    if (tid < 64) {
        int hits = 0;
        for (int i = tid; i < 128; i += 64) {
            ushort_t w = xprobe[2 * i];
            uint hb = (w >> 8) & 0x7f;
            hits += (hb >= 0x38 && hb <= 0x42) ? 1 : 0;
        }
        #pragma unroll
        for (int off = 32; off >= 1; off >>= 1) hits += __shfl_xor(hits, off);
        if (tid == 0) s_isbf = (hits >= 64) ? 1 : 0;
    }
    __syncthreads();
    int isbf = s_isbf;
    int b = blockIdx.x;
    if (b == 0 && tid == 0) *flag = isbf;

    if (b < NBZ) {                       // zero deg (int4)
        int i0 = (b * 256 + tid) * 4;
        if (i0 + 4 <= N) *(int4*)&deg[i0] = make_int4(0, 0, 0, 0);
        else for (int j = 0; j < 4; ++j) if (i0 + j < N) deg[i0 + j] = 0;
        return;
    }
    if (b < NBZ + 15) {                  // canon small4
        int idx = (b - NBZ) * 256 + tid;
        const void* srcs[4] = {a0, a1, a2, a3};
        ushort_t* dsts[4] = {o0, o1, o2, o3};
        int ns[4] = {n0, n1, n2, n3};
        #pragma unroll
        for (int k = 0; k < 4; ++k) {
            if (idx < ns[k]) {
                dsts[k][idx] = isbf ? ((const ushort_t*)srcs[k])[idx]
                                    : f2bf(((const float*)srcs[k])[idx]);
                return;
            }
            idx -= ns[k];
        }
        return;
    }
    if (isbf) return;                    // x used directly when already bf16
    long long i0 = ((long long)(b - NBZ - 15) * 256 + tid) * 8;
    if (i0 + 8 <= nx) {
        const float* f = (const float*)xin + i0;
        float4 a = *(const float4*)f, bb = *(const float4*)(f + 4);
        ushort_t o[8] = {f2bf(a.x), f2bf(a.y), f2bf(a.z), f2bf(a.w),
                         f2bf(bb.x), f2bf(bb.y), f2bf(bb.z), f2bf(bb.w)};
        *(uint4*)&xc[i0] = *(uint4*)o;
    } else {
        for (long long i = i0; i < nx; ++i) xc[i] = f2bf(((const float*)xin)[i]);
    }
}

// ---------------------------------------------------------------------------
// CSR build by dst
// ---------------------------------------------------------------------------
__global__ void hist_kernel(const int* __restrict__ dst, int* deg, int E, int N) {
    int i = blockIdx.x * blockDim.x + threadIdx.x;
    if (i < E) {
        int d = dst[i];
        if ((uint)d < (uint)N) atomicAdd(&deg[d], 1);
    }
}

// phase 1: per-1024-block exclusive scan over (deg[i] + 1)  [+1 = self-loop]
__global__ __launch_bounds__(256) void scan1(const int* __restrict__ deg, int* __restrict__ part,
                                             int* __restrict__ bsum, int N) {
    __shared__ int tmp[256];
    int b = blockIdx.x, tid = threadIdx.x;
    int i0 = b * 1024 + tid * 4;
    int v[4] = {0, 0, 0, 0};
    if (i0 + 4 <= N) { int4 q = *(const int4*)&deg[i0]; v[0]=q.x+1; v[1]=q.y+1; v[2]=q.z+1; v[3]=q.w+1; }
    else { for (int j = 0; j < 4; ++j) v[j] = (i0 + j < N) ? deg[i0 + j] + 1 : 0; }
    int s0 = v[0], s1 = s0 + v[1], s2 = s1 + v[2], s3 = s2 + v[3];
    tmp[tid] = s3;
    __syncthreads();
    for (int off = 1; off < 256; off <<= 1) {
        int t = (tid >= off) ? tmp[tid - off] : 0;
        __syncthreads();
        tmp[tid] += t;
        __syncthreads();
    }
    int base = tid ? tmp[tid - 1] : 0;
    int e[4] = {base, base + s0, base + s1, base + s2};
    if (i0 + 4 <= N) { *(int4*)&part[i0] = make_int4(e[0], e[1], e[2], e[3]); }
    else { for (int j = 0; j < 4; ++j) if (i0 + j < N) part[i0 + j] = e[j]; }
    if (tid == 255) bsum[b] = tmp[255];
}

// phase 2 (fused): each block wave-scans the Nb block sums itself (Nb <= 64)
__global__ __launch_bounds__(256) void scan3(const int* __restrict__ part, const int* __restrict__ bsum,
                                             int* __restrict__ offsets, int* __restrict__ cursor,
                                             int N, int Nb) {
    __shared__ int s_add, s_tot;
    int b = blockIdx.x, tid = threadIdx.x;
    if (tid < 64) {
        int v = (tid < Nb) ? bsum[tid] : 0;
        int incl = v;
        #pragma unroll
        for (int off = 1; off < 64; off <<= 1) {
            int t = __shfl_up(incl, off);
            if (tid >= off) incl += t;
        }
        if (tid == b) s_add = incl - v;
        if (tid == Nb - 1) s_tot = incl;
    }
    __syncthreads();
    int add = s_add;
    int i0 = b * 1024 + tid * 4;
    #pragma unroll
    for (int j = 0; j < 4; ++j) {
        int i = i0 + j;
        if (i < N) { int o = part[i] + add; offsets[i] = o; cursor[i] = o; }
    }
    if (b == Nb - 1 && tid == 0) offsets[N] = s_tot;   // = E + N
}

__global__ void scatter_kernel(const int* __restrict__ src, const int* __restrict__ dst,
                               int* cursor, int* srcs, int E, int N) {
    int i = blockIdx.x * blockDim.x + threadIdx.x;
    if (i >= E + N) return;
    int s, d;
    if (i < E) { s = src[i]; d = dst[i]; }
    else       { s = i - E; d = i - E; }   // self-loop
    if ((uint)d >= (uint)N) return;
    int pos = atomicAdd(&cursor[d], 1);
    if ((uint)pos < (uint)(E + N)) srcs[pos] = s;
}

// ---------------------------------------------------------------------------
// dual-dtype transpose+canon for BOTH weight matrices in one dispatch (z = 0/1)
// out[N][K] (bf16) = in[K][N] (bf16 or fp32)
// ---------------------------------------------------------------------------
__global__ __launch_bounds__(256) void transpose_canon2(const void* __restrict__ inL,
                                                        const void* __restrict__ inR,
                                                        ushort_t* __restrict__ outL,
                                                        ushort_t* __restrict__ outR,
                                                        const int* __restrict__ flag,
                                                        int K, int N) {
    __shared__ ushort_t t[64][72];
    const void* in = blockIdx.z ? inR : inL;
    ushort_t* outp = blockIdx.z ? outR : outL;
    int k0 = blockIdx.y * 64, n0 = blockIdx.x * 64;
    int tid = threadIdx.x;
    int r = tid >> 3;            // 0..31
    int c = (tid & 7) * 8;       // 0,8,..,56
    int isbf = *flag;
    #pragma unroll
    for (int p = 0; p < 2; ++p) {
        int row = r + p * 32;
        size_t base = (size_t)(k0 + row) * N + n0 + c;
        if (isbf) {
            *(uint4*)&t[row][c] = *(const uint4*)((const ushort_t*)in + base);
        } else {
            const float* f = (const float*)in + base;
            float4 a = *(const float4*)f, b = *(const float4*)(f + 4);
            ushort_t o[8] = {f2bf(a.x), f2bf(a.y), f2bf(a.z), f2bf(a.w),
                             f2bf(b.x), f2bf(b.y), f2bf(b.z), f2bf(b.w)};
            *(uint4*)&t[row][c] = *(uint4*)o;
        }
    }
    __syncthreads();
    #pragma unroll
    for (int p = 0; p < 2; ++p) {
        int row = r + p * 32;
        #pragma unroll
        for (int j = 0; j < 8; ++j)
            outp[(size_t)(n0 + row) * K + k0 + c + j] = t[c + j][row];
    }
}

// ---------------------------------------------------------------------------
// R2: 256x256 8-phase MFMA GEMM (learn_hip m201 structure, re-derived).
// C[M,N] = A[M,K] @ Bt[N,K]^T, all bf16, fp32 acc.
// 512 threads = 8 waves (2M x 4N); per-wave output 128x64 = 8x4 frags.
// LDS 128KB = 2 K-tile buffers x (A 32KB + B 32KB), BK=64.
// XOR swizzle: LDS[r][cb] holds tile[r][cb ^ ((r&7)<<4)] (byte offsets),
// realized by pre-swizzling the per-lane GLOBAL source (global_load_lds dest
// must stay linear: uniform base + lane*16). ds_reads apply the same XOR.
// Phase (x8 per 2 K-tiles): {ds_read frags; s_barrier; stage-issue (freed
// regions only); lgkmcnt(0); setprio(1); 16 MFMA; setprio(0); [vmcnt]; s_barrier}.
// Staging ledger: B of buf p freed at phase-0 barrier (all B frags read ph0);
// A freed at phase-3 barrier. So ph0 stages next B, ph3 stages next A.
// vmcnt(8) BEFORE the closing barrier of ph3/ph7 => barrier upgrades the
// per-wave wait to an all-waves data guarantee for the next tile's reads.
// Last pair drains with vmcnt(0) at ph3. Never __syncthreads in the loop
// (it would emit vmcnt(0) and kill the pipeline).
// Epilogue reuses LDS: stride-264 bounce, two 128-row passes, 16B stores.
// ---------------------------------------------------------------------------
__global__ __launch_bounds__(512, 2) void gemm256(const ushort_t* A_bf, const ushort_t* A_cv,
                                                  const int* __restrict__ flag,
                                                  const ushort_t* __restrict__ Bt,
                                                  ushort_t* __restrict__ C,
                                                  int M, int Nn, int K) {
    __shared__ ushort_t SH[65536];            // 131072 B: [A0|B0|A1|B1] x 16384 elems
    const ushort_t* A = (*flag) ? A_bf : A_cv;
    int tid = threadIdx.x;
    int lane = tid & 63, wave = tid >> 6;
    int wm = wave >> 2, wn = wave & 3;        // 2 x 4 wave grid
    int row0 = blockIdx.y * 256, col0 = blockIdx.x * 256;

    f32x4v acc[8][4];
    #pragma unroll
    for (int i = 0; i < 8; ++i)
        #pragma unroll
        for (int j = 0; j < 4; ++j) acc[i][j] = (f32x4v){0.f, 0.f, 0.f, 0.f};

    // ---- staging precompute ----
    // line hl (0..3) covers LDS rows [hl*64, hl*64+64); thread t -> row hl*64 + (t>>3),
    // col-byte (t&7)*16, source pre-swizzled: cb ^ ((row&7)<<4). (t>>3)&7 == row&7.
    int rlo = tid >> 3;                                        // 0..63
    int selem = ((((tid & 7) << 4) ^ ((rlo & 7) << 4)) >> 1);  // swizzled col, elems
    int arow[4]; const ushort_t* bsrc[4];
    #pragma unroll
    for (int hl = 0; hl < 4; ++hl) {
        int r = hl * 64 + rlo;
        int ga = row0 + r; if (ga >= M) ga = M - 1;            // tail clamp (C guarded)
        arow[hl] = ga;
        bsrc[hl] = Bt + (size_t)(col0 + r) * K + selem;        // col0+255 < Nn always
    }
    int doff = tid * 8;                                        // elems within 4K-elem line

    auto STAGE_A = [&](int kt) {                               // 4 vmem lines
        ushort_t* dst = &SH[(kt & 1) * 32768];
        int ke = kt * 64 + selem;
        #pragma unroll
        for (int hl = 0; hl < 4; ++hl)
            __builtin_amdgcn_global_load_lds((g_u32_t*)(A + (size_t)arow[hl] * K + ke),
                                             (lds_u32_t*)(dst + hl * 4096 + doff), 16, 0, 0);
    };
    auto STAGE_B = [&](int kt) {                               // 4 vmem lines
        ushort_t* dst = &SH[(kt & 1) * 32768 + 16384];
        int kof = kt * 64;
        #pragma unroll
        for (int hl = 0; hl < 4; ++hl)
            __builtin_amdgcn_global_load_lds((g_u32_t*)(bsrc[hl] + kof),
                                             (lds_u32_t*)(dst + hl * 4096 + doff), 16, 0, 0);
    };

    // ---- fragment read offsets (swizzled) ----
    int fm = lane & 15;
    int co[2];
    {   int cb0 = (lane >> 4) << 4;          // 16B slot within K=32 half
        int xm = (lane & 7) << 4;            // row&7 == lane&7 for frag rows
        co[0] = ((cb0) ^ xm) >> 1;
        co[1] = ((64 + cb0) ^ xm) >> 1;
    }
    bf16x8v bF[4][2];

#define PHASE(q, PBASE, STAGE_STMT, TAIL_STMT) do {                               \
        if ((q) == 0) {                                                           \
            _Pragma("unroll") for (int nj = 0; nj < 4; ++nj)                      \
                _Pragma("unroll") for (int s = 0; s < 2; ++s)                     \
                    bF[nj][s] = *(const bf16x8v*)&SH[(PBASE) + 16384 +            \
                                    (wn * 64 + nj * 16 + fm) * 64 + co[s]];       \
        }                                                                         \
        bf16x8v aF[2][2];                                                         \
        _Pragma("unroll") for (int u = 0; u < 2; ++u)                             \
            _Pragma("unroll") for (int s = 0; s < 2; ++s)                         \
                aF[u][s] = *(const bf16x8v*)&SH[(PBASE) +                         \
                               (wm * 128 + (q) * 32 + u * 16 + fm) * 64 + co[s]]; \
        asm volatile("s_barrier" ::: "memory");                                   \
        STAGE_STMT;                                                               \
        asm volatile("s_waitcnt lgkmcnt(0)" ::: "memory");                        \
        __builtin_amdgcn_sched_barrier(0);                                        \
        __builtin_amdgcn_s_setprio(1);                                            \
        _Pragma("unroll") for (int u = 0; u < 2; ++u)                             \
            _Pragma("unroll") for (int nj = 0; nj < 4; ++nj)                      \
                _Pragma("unroll") for (int s = 0; s < 2; ++s)                     \
                    acc[(q) * 2 + u][nj] = __builtin_amdgcn_mfma_f32_16x16x32_bf16( \
                        aF[u][s], bF[nj][s], acc[(q) * 2 + u][nj], 0, 0, 0);      \
        __builtin_amdgcn_s_setprio(0);                                            \
        __builtin_amdgcn_sched_barrier(0);                                        \
        TAIL_STMT;                                                                \
        asm volatile("s_barrier" ::: "memory");                                   \
    } while (0)

    int NK = K >> 6;                           // 8 for K=512 (even)
    // prologue: tiles 0,1 fully staged; vmcnt(8)+barrier => tile0 landed everywhere
    STAGE_B(0); STAGE_A(0); STAGE_B(1); STAGE_A(1);
    asm volatile("s_waitcnt vmcnt(8)" ::: "memory");
    asm volatile("s_barrier" ::: "memory");

    for (int kt = 0; kt < NK; kt += 2) {
        int lastpair = (kt + 2 >= NK);
        // tile kt (parity 0)
        PHASE(0, 0, { if (!lastpair) STAGE_B(kt + 2); }, {});
        PHASE(1, 0, {}, {});
        PHASE(2, 0, {}, {});
        PHASE(3, 0, { if (!lastpair) STAGE_A(kt + 2); },
                    { if (lastpair) { asm volatile("s_waitcnt vmcnt(0)" ::: "memory"); }
                      else          { asm volatile("s_waitcnt vmcnt(8)" ::: "memory"); } });
        // tile kt+1 (parity 1)
        PHASE(0, 32768, { if (!lastpair) STAGE_B(kt + 3); }, {});
        PHASE(1, 32768, {}, {});
        PHASE(2, 32768, {}, {});
        PHASE(3, 32768, { if (!lastpair) STAGE_A(kt + 3); },
                        { if (!lastpair) { asm volatile("s_waitcnt vmcnt(8)" ::: "memory"); } });
    }
#undef PHASE

    // ---- epilogue: bounce C through LDS (stride 264 elems), 2 row-half passes ----
    int rq = (lane >> 4) * 4;
    #pragma unroll
    for (int hh = 0; hh < 2; ++hh) {
        if (wm == hh) {
            #pragma unroll
            for (int mi = 0; mi < 8; ++mi)
                #pragma unroll
                for (int rr = 0; rr < 4; ++rr)
                    #pragma unroll
                    for (int nj = 0; nj < 4; ++nj)
                        SH[(mi * 16 + rq + rr) * 264 + wn * 64 + nj * 16 + fm] =
                            f2bf(acc[mi][nj][rr]);
        }
        __syncthreads();                       // safe: staging queue fully drained
        #pragma unroll
        for (int j = 0; j < 8; ++j) {
            int idx = tid + j * 512;           // 0..4095 -> 128 rows x 32 uint4
            int r = idx >> 5, c = (idx & 31) * 8;
            int gm = row0 + hh * 128 + r;
            if (gm < M)
                *(uint4*)&C[(size_t)gm * Nn + col0 + c] = *(const uint4*)&SH[r * 264 + c];
        }
        __syncthreads();
    }
}

// ---------------------------------------------------------------------------
// Fused edge/softmax/aggregate/mean-heads/bias/classifier (R1 layout: 2 waves
// per dst node, 2 heads per wave, 16 ch/lane). OUTPUT FP32.
// ---------------------------------------------------------------------------
__global__ __launch_bounds__(128, 4) void gat_aggregate(
    const ushort_t* __restrict__ xl, int xl_stride,
    const ushort_t* __restrict__ xr, int xr_stride,
    const int* __restrict__ offsets, const int* __restrict__ srcs,
    const ushort_t* __restrict__ att, const ushort_t* __restrict__ bias,
    const ushort_t* __restrict__ Wc, const ushort_t* __restrict__ bc,
    float* __restrict__ out, int c0, int Cn, int N, int EN) {
    int bn = blockIdx.x;
    if (bn >= Cn) return;
    int n = c0 + bn;
    int tid = threadIdx.x;
    int w = tid >> 6, lane = tid & 63;
    int h = 2 * w + (lane >> 5);             // this lane's head
    int r = lane & 31;                       // 32 lanes per head
    int hoff = h * FEAT + r * 16;            // 16 channels per lane

    __shared__ float sh[HEADS][FEAT];
    __shared__ float r0s[2], r1s[2];

    float2 xrr[8], attr[8];
    { const ushort_t* p = &xr[(size_t)bn * xr_stride + hoff];
      uint4 qa = *(const uint4*)p, qb = *(const uint4*)(p + 8);
      xrr[0] = up2(qa.x); xrr[1] = up2(qa.y); xrr[2] = up2(qa.z); xrr[3] = up2(qa.w);
      xrr[4] = up2(qb.x); xrr[5] = up2(qb.y); xrr[6] = up2(qb.z); xrr[7] = up2(qb.w); }
    { const ushort_t* p = &att[hoff];
      uint4 qa = *(const uint4*)p, qb = *(const uint4*)(p + 8);
      attr[0] = up2(qa.x); attr[1] = up2(qa.y); attr[2] = up2(qa.z); attr[3] = up2(qa.w);
      attr[4] = up2(qb.x); attr[5] = up2(qb.y); attr[6] = up2(qb.z); attr[7] = up2(qb.w); }

    int start = offsets[n], end = offsets[n + 1];
    start = max(0, min(start, EN));
    end   = max(start, min(end, EN));
    int deg = end - start;

    int sv = 0;
    if (lane < deg) sv = srcs[start + lane];

    float l = 0.f;
    float2 acc[8] = {{0.f,0.f},{0.f,0.f},{0.f,0.f},{0.f,0.f},
                     {0.f,0.f},{0.f,0.f},{0.f,0.f},{0.f,0.f}};
    const ushort_t* xlh = xl + hoff;
    const float2 cneg = make_float2(NEG - 1.0f, NEG - 1.0f);

    auto getS = [&](int i) -> int {
        if (i >= deg) i = deg - 1;
        if (i < 0) i = 0;
        int s = (i < 64) ? __shfl(sv, i) : srcs[start + i];
        return ((uint)s >= (uint)N) ? 0 : s;
    };
    auto fetchE = [&](int i, uint4& qa, uint4& qb) {
        int s = getS(i);
        const ushort_t* pp = xlh + (size_t)s * xl_stride;
        qa = *(const uint4*)pp;
        qb = *(const uint4*)(pp + 8);
    };
    auto body = [&](uint4 qa, uint4 qb) {
        float2 v[8] = {up2(qa.x), up2(qa.y), up2(qa.z), up2(qa.w),
                       up2(qb.x), up2(qb.y), up2(qb.z), up2(qb.w)};
        float2 p2 = make_float2(0.f, 0.f);
        #pragma unroll
        for (int j = 0; j < 8; ++j) {
            float2 u  = f2add(v[j], xrr[j]);
            float2 lr = f2fma(f2min0(u), cneg, u);   // 2-op LeakyReLU (packed)
            p2 = f2fma(lr, attr[j], p2);
        }
        float p = p2.x + p2.y;
        #pragma unroll
        for (int off = 16; off >= 1; off >>= 1) p += __shfl_xor(p, off);  // intra-half
        float wgt = __expf(p);
        l += wgt;
        #pragma unroll
        for (int j = 0; j < 8; ++j) acc[j] = f2fmas(wgt, v[j], acc[j]);
    };

    uint4 a0q, a0r, a1q, a1r, b0q, b0r, b1q, b1r;
    fetchE(0, a0q, a0r);
    fetchE(1, a1q, a1r);
    for (int e = 0; e < deg; e += 2) {
        fetchE(e + 2, b0q, b0r);     // clamped on tail -> L1 hit, discarded
        fetchE(e + 3, b1q, b1r);
        body(a0q, a0r);
        if (e + 1 < deg) body(a1q, a1r);
        a0q = b0q; a0r = b0r; a1q = b1q; a1r = b1r;
    }

    float inv = 0.25f / fmaxf(l, 1e-35f);   // 1/l, mean over heads folded in
    #pragma unroll
    for (int j = 0; j < 8; ++j) {
        sh[h][r * 16 + 2 * j]     = acc[j].x * inv;
        sh[h][r * 16 + 2 * j + 1] = acc[j].y * inv;
    }
    __syncthreads();

    float p0 = 0.f, p1 = 0.f;
    #pragma unroll
    for (int c = tid; c < FEAT; c += 128) {
        float f = sh[0][c] + sh[1][c] + sh[2][c] + sh[3][c] + bf2f(bias[c]);
        uint w2 = *(const uint*)&Wc[c * 2];
        p0 = fmaf(f, bf2f((ushort_t)(w2 & 0xffff)), p0);
        p1 = fmaf(f, bf2f((ushort_t)(w2 >> 16)), p1);
    }
    #pragma unroll
    for (int off = 32; off >= 1; off >>= 1) {
        p0 += __shfl_xor(p0, off);
        p1 += __shfl_xor(p1, off);
    }
    if (lane == 0) { r0s[w] = p0; r1s[w] = p1; }
    __syncthreads();
    if (tid == 0) {
        out[(size_t)n * 2 + 0] = r0s[0] + r0s[1] + bf2f(bc[0]);
        out[(size_t)n * 2 + 1] = r1s[0] + r1s[1] + bf2f(bc[1]);
    }
}

// ---------------------------------------------------------------------------
extern "C" void kernel_launch(void* const* d_in, const int* in_sizes, int n_in,
                              void* d_out, int out_size, void* d_ws, size_t ws_size,
                              hipStream_t stream) {
    const void* x    = d_in[0];
    const int*  ei   = (const int*)d_in[1];
    const void* W_l  = d_in[2];
    const void* W_r  = d_in[3];
    const void* att  = d_in[4];
    const void* bias = d_in[5];
    const void* Wc   = d_in[6];
    const void* bc   = d_in[7];
    float* out = (float*)d_out;

    const int N  = in_sizes[0] / FEAT;     // 20000
    const int E  = in_sizes[1] / 2;        // 160000
    const int K  = FEAT;                   // 512
    const int HC = HEADS * FEAT;           // 2048
    const int EN = E + N;
    const int Nb = (N + 1023) / 1024;      // scan blocks (20 <= 64)

    const int* src = ei;
    const int* dst = ei + E;

    // ---- adaptive workspace layout ----
    char* base = (char*)d_ws;
    size_t off = 0;
    auto alloc = [&](size_t bytes) -> char* {
        char* p = base + off;
        off = (off + bytes + 255) & ~(size_t)255;
        return p;
    };
    int* flag    = (int*)alloc(4);
    int* offsets = (int*)alloc((size_t)(N + 1) * 4);
    int* cursor  = (int*)alloc((size_t)N * 4);
    int* deg     = (int*)alloc((size_t)N * 4);
    int* part    = (int*)alloc((size_t)N * 4);
    int* bsum    = (int*)alloc((size_t)(Nb + 1) * 4);
    int* srcs    = (int*)alloc((size_t)EN * 4);
    ushort_t* attc  = (ushort_t*)alloc((size_t)HC * 2);
    ushort_t* biasc = (ushort_t*)alloc((size_t)FEAT * 2);
    ushort_t* Wcc   = (ushort_t*)alloc((size_t)FEAT * 2 * 2);
    ushort_t* bcc   = (ushort_t*)alloc(2 * 2);
    ushort_t* xc   = (ushort_t*)alloc((size_t)N * K * 2);
    ushort_t* Wcat = (ushort_t*)alloc((size_t)2 * HC * K * 2);   // [Wl^T ; Wr^T]
    size_t fixed = off;

    size_t need_merged = (size_t)N * 2 * HC * 2;
    bool merged = (ws_size >= fixed + need_merged);

    // 0) fused prep: probe + deg-zero + small canon + x canon (1 dispatch)
    long long NX = (long long)N * K;
    const int NBZ = (N + 1023) / 1024;                       // deg-zero blocks
    int nxb = (int)((NX / 8 + 255) / 256);                   // x canon blocks
    prep_kernel<<<NBZ + 15 + nxb, 256, 0, stream>>>(
        (const ushort_t*)x, flag, deg, N, NBZ,
        att, attc, HC, bias, biasc, FEAT, Wc, Wcc, FEAT * 2, bc, bcc, 2,
        x, xc, NX);

    // 1) CSR build
    hist_kernel<<<(E + 255) / 256, 256, 0, stream>>>(dst, deg, E, N);
    scan1<<<Nb, 256, 0, stream>>>(deg, part, bsum, N);
    scan3<<<Nb, 256, 0, stream>>>(part, bsum, offsets, cursor, N, Nb);
    scatter_kernel<<<(EN + 255) / 256, 256, 0, stream>>>(src, dst, cursor, srcs, E, N);

    // 2) transpose+canon both weights in one dispatch
    dim3 tg(HC / 64, K / 64, 2);
    transpose_canon2<<<tg, 256, 0, stream>>>(W_l, W_r, Wcat, Wcat + (size_t)HC * K,
                                             flag, K, HC);

    const ushort_t* x_bf = (const ushort_t*)x;

    if (merged) {
        ushort_t* xlr = (ushort_t*)(base + fixed);       // N x 4096: [xl | xr]
        dim3 gg(2 * HC / 256, (N + 255) / 256);          // 16 x 79
        gemm256<<<gg, 512, 0, stream>>>(x_bf, xc, flag, Wcat, xlr, N, 2 * HC, K);
        gat_aggregate<<<N, 128, 0, stream>>>(xlr, 2 * HC, xlr + HC, 2 * HC,
                                             offsets, srcs, attc, biasc, Wcc, bcc,
                                             out, 0, N, N, EN);
    } else {
        // fallback: separate xl + chunked xr
        ushort_t* xl = (ushort_t*)alloc((size_t)N * HC * 2);
        size_t remain = (ws_size > off) ? (ws_size - off) : 0;
        long long Cmax = (long long)(remain / ((size_t)HC * 2));
        int C = (Cmax >= N) ? N : (int)(Cmax & ~255LL);
        if (C < 256) C = 256;
        ushort_t* xrc = (ushort_t*)(base + off);
        ushort_t* Wlt = Wcat;
        ushort_t* Wrt = Wcat + (size_t)HC * K;

        dim3 gl(HC / 256, (N + 255) / 256);
        gemm256<<<gl, 512, 0, stream>>>(x_bf, xc, flag, Wlt, xl, N, HC, K);
        for (int c0 = 0; c0 < N; c0 += C) {
            int Cn = (N - c0 < C) ? (N - c0) : C;
            dim3 gr(HC / 256, (Cn + 255) / 256);
            gemm256<<<gr, 512, 0, stream>>>(x_bf + (size_t)c0 * K, xc + (size_t)c0 * K, flag,
                                            Wrt, xrc, Cn, HC, K);
            gat_aggregate<<<Cn, 128, 0, stream>>>(xl, HC, xrc, HC,
                                                  offsets, srcs, attc, biasc, Wcc, bcc,
                                                  out, c0, Cn, N, EN);
        }
    }
}